// Round 3
// baseline (6870.959 us; speedup 1.0000x reference)
//
#include <hip/hip_runtime.h>
#include <stdint.h>

// Stage2 neural-dynamics simulator, MI355X — round 3.
// 64 blocks (one per batch), 960 threads (3 parts x 320 rank slots, 15 waves).
// NEW: (1) each thread's entry slice lives in VGPRs (compile-time caps per
// state-wave, fully unrolled gather loop) -> zero L2 traffic in the t-loop.
// (2) prep counting-sorts each row-part's entries by LDS bank and rotates by a
// lane-dependent phase so each wave-slot's 64 gathers spread ~2/bank (free).
// Stim GEMM DT*(x@b^T + I0) precomputed into d_out.

#define NN      300
#define PTPB    320
#define STPB    960
#define TSTEPS  1000
#define DDIM    32
#define BATCH   64
#define DTC     0.01f
#define UCLIP   35.0f

#define CAP_0   80
#define CAP_1   72
#define CAP_2   68
#define CAP_3   64
#define CAP_4   60
__host__ __device__ __forceinline__ int capOf(int sw){
  return sw==0?CAP_0: sw==1?CAP_1: sw==2?CAP_2: sw==3?CAP_3: CAP_4;
}

// pad entry for rank rr: val=0 (top16), target zs[900+(rr&31)] (zeroed region)
#define PADOFF(rr) ((uint32_t)(3600 + (((rr)&31)<<2)))

// ws layout (bytes)
#define ENT_OFF   0
#define ENT_BYTES (CAP_0*STPB*4)           // 307200
#define CR_OFF    (ENT_OFF+ENT_BYTES)      // f32[320]  c = lam - DT*G*deg (rank order)
#define RR_OFF    (CR_OFF+PTPB*4)          // u32[320]  rank -> row
#define META_OFF  (RR_OFF+PTPB*4)          // f32[8]    alpha x4, gamma x4
#define LEN_OFF   (META_OFF+8*4)           // u32[320]  row nnz
#define DEG_OFF   (LEN_OFF+PTPB*4)         // f32[300]  gap degree
#define RANK_OFF  (DEG_OFF+NN*4)           // u32[300]  row -> rank

__device__ __forceinline__ float sigmoidf_(float x){ return 1.0f/(1.0f+__expf(-x)); }
__device__ __forceinline__ float softplusf_(float x){ return x>15.f ? x : log1pf(__expf(x)); }
__device__ __forceinline__ uint32_t bf16bits(float f){
  uint32_t v = __float_as_uint(f);
  return (v + 0x7FFFu + ((v>>16)&1u)) >> 16;   // RN-even
}

// ---------- prep A: per-row nnz + gap degree (grid 300 x 64) ----------
__global__ __launch_bounds__(64) void prepA_kernel(
    const float* __restrict__ Te, const float* __restrict__ Tsv,
    const float* __restrict__ Tdcv, uint8_t* __restrict__ ws)
{
  int i = blockIdx.x, lane = threadIdx.x;
  const float* te  = Te   + (size_t)i*NN;
  const float* tsv = Tsv  + (size_t)i*NN;
  const float* tdv = Tdcv + (size_t)i*NN;
  uint32_t cnt = 0; float deg = 0.f;
  for (int j=lane; j<NN; j+=64){
    float e = te[j];
    deg += e;
    cnt += (tsv[j]>0.f) + (tdv[j]>0.f) + (e>0.f);
  }
  for (int off=32; off; off>>=1){
    cnt += __shfl_down(cnt, off);
    deg += __shfl_down(deg, off);
  }
  if (lane==0){
    ((uint32_t*)(ws+LEN_OFF))[i] = cnt;
    ((float*)(ws+DEG_OFF))[i]    = deg;
  }
}

// ---------- prep B: ranking + scalars (1 block x 320) ----------
__global__ __launch_bounds__(PTPB) void prepB_kernel(
    const float* __restrict__ lamr, const float* __restrict__ Gr,
    const float* __restrict__ asvr, const float* __restrict__ tausvr,
    const float* __restrict__ adcvr, const float* __restrict__ taudcvr,
    uint8_t* __restrict__ ws)
{
  __shared__ uint32_t len_s[PTPB];
  __shared__ uint32_t rr_s[PTPB];
  int tid = threadIdx.x;
  uint32_t* LEN  = (uint32_t*)(ws+LEN_OFF);
  float*    DEG  = (float*)(ws+DEG_OFF);
  uint32_t* RANK = (uint32_t*)(ws+RANK_OFF);
  uint32_t* RR   = (uint32_t*)(ws+RR_OFF);
  float*    CR   = (float*)(ws+CR_OFF);
  float*    META = (float*)(ws+META_OFF);

  len_s[tid] = (tid<NN) ? LEN[tid] : 0u;
  rr_s[tid]  = 0xFFFFFFFFu;
  __syncthreads();
  uint32_t rank = 0;
  if (tid < NN){
    uint32_t li = len_s[tid];
    for (int j=0;j<NN;++j){
      uint32_t lj = len_s[j];
      rank += (lj>li || (lj==li && j<tid)) ? 1u:0u;
    }
    rr_s[rank] = (uint32_t)tid;
    RANK[tid]  = rank;
  }
  __syncthreads();
  RR[tid] = rr_s[tid];
  float G = 2.0f * sigmoidf_(Gr[0]);
  if (tid < NN){
    float lam = 0.9999f * sigmoidf_(lamr[tid]);
    CR[rank] = lam - DTC*G*DEG[tid];
  } else {
    CR[tid] = 0.f;
  }
  if (tid < 4){
    const float* ar = (tid<2)? asvr   : adcvr;
    const float* tr = (tid<2)? tausvr : taudcvr;
    int kk = tid & 1;
    float a   = 10.0f * sigmoidf_(ar[kk]);
    float tau = softplusf_(tr[kk]) + 1e-4f;
    float al  = __expf(-DTC/tau);
    META[tid]   = al;
    META[4+tid] = a*(1.0f-al);   // track s' = a*s
  }
}

// ---------- prep C: emit bank-scheduled entries (grid 320 x 64) ----------
#define LISTCAP 252
__global__ __launch_bounds__(64) void prepC_kernel(
    const float* __restrict__ Te,  const float* __restrict__ Tsv,
    const float* __restrict__ Tdcv,const float* __restrict__ Wsv,
    const float* __restrict__ Wdcv,const float* __restrict__ Gr,
    const int*   __restrict__ signt, uint8_t* __restrict__ ws)
{
  __shared__ uint32_t list[LISTCAP];
  __shared__ uint32_t srt[96];
  __shared__ uint32_t cnt[33];
  int rr = blockIdx.x, lane = threadIdx.x;
  uint32_t* ENT = (uint32_t*)(ws+ENT_OFF);
  const uint32_t* RR = (const uint32_t*)(ws+RR_OFF);
  int sw  = rr >> 6;
  int cap = capOf(sw);
  uint32_t row = RR[rr];

  if (row >= NN){                       // unowned rank slots: all pad
    for (int p=0;p<3;++p)
      for (int k=lane;k<cap;k+=64)
        ENT[(size_t)k*STPB + p*PTPB + rr] = PADOFF(rr);
    return;
  }

  float G = 2.0f * sigmoidf_(Gr[0]);
  const float* te  = Te   + (size_t)row*NN;
  const float* tsv = Tsv  + (size_t)row*NN;
  const float* tdv = Tdcv + (size_t)row*NN;
  const float* wsv = Wsv  + (size_t)row*NN;
  const float* wdv = Wdcv + (size_t)row*NN;
  uint64_t lmask = ((uint64_t)1 << lane) - 1;
  uint32_t k = 0;
  for (int c0=0; c0<NN; c0+=64){       // SV segment
    int j = c0 + lane;
    bool on = (j<NN) && (tsv[j] > 0.f);
    uint64_t bal = __ballot(on);
    if (on){
      uint32_t s = k + (uint32_t)__popcll(bal & lmask);
      if (s < LISTCAP){
        float sg = 2.0f*(float)signt[j] - 1.0f;
        float v  = DTC * sg * softplusf_(wsv[j]);
        list[s] = (bf16bits(v)<<16) | (uint32_t)(j*4);
      }
    }
    k += (uint32_t)__popcll(bal);
  }
  for (int c0=0; c0<NN; c0+=64){       // DCV segment
    int j = c0 + lane;
    bool on = (j<NN) && (tdv[j] > 0.f);
    uint64_t bal = __ballot(on);
    if (on){
      uint32_t s = k + (uint32_t)__popcll(bal & lmask);
      if (s < LISTCAP){
        float sg = 2.0f*(float)signt[j] - 1.0f;
        float v  = DTC * sg * softplusf_(wdv[j]);
        list[s] = (bf16bits(v)<<16) | (uint32_t)((NN+j)*4);
      }
    }
    k += (uint32_t)__popcll(bal);
  }
  for (int c0=0; c0<NN; c0+=64){       // TE (gap) segment
    int j = c0 + lane;
    bool on = (j<NN) && (te[j] > 0.f);
    uint64_t bal = __ballot(on);
    if (on){
      uint32_t s = k + (uint32_t)__popcll(bal & lmask);
      if (s < LISTCAP){
        float v = DTC * G * te[j];
        list[s] = (bf16bits(v)<<16) | (uint32_t)((2*NN+j)*4);
      }
    }
    k += (uint32_t)__popcll(bal);
  }
  if (k > LISTCAP) k = LISTCAP;
  __syncthreads();

  if (lane == 0){
    for (int p=0; p<3; ++p){
      // counting sort of part-p entries (s%3==p) by LDS bank
      for (int b2=0;b2<33;++b2) cnt[b2]=0;
      for (uint32_t s=p; s<k; s+=3) cnt[1 + ((list[s]>>2)&31)]++;
      for (int b2=0;b2<32;++b2) cnt[b2+1] += cnt[b2];
      int Lp = 0;
      for (uint32_t s=p; s<k; s+=3){
        uint32_t e = list[s];
        uint32_t pos = cnt[(e>>2)&31]++;
        if (pos < 96) srt[pos] = e;
        Lp++;
      }
      if (Lp > cap) Lp = cap;          // truncation guard (unreachable w/ margins)
      // rotated placement: slot reads sorted[(slot+phase)%Lp]
      int phase = ((rr&31)*Lp) >> 5;
      for (int j=0;j<Lp;++j){
        int slot = j - phase; if (slot < 0) slot += Lp;
        ENT[(size_t)slot*STPB + p*PTPB + rr] = srt[j];
      }
      for (int kk=Lp; kk<cap; ++kk)
        ENT[(size_t)kk*STPB + p*PTPB + rr] = PADOFF(rr);
    }
  }
}

// ---------- stimulus: d_out[b,t,i] = DT * (dot(x[b,t,:], bmat[i,:]) + I0[i]) ----------
__global__ __launch_bounds__(256) void stim_kernel(
    const float* __restrict__ x, const float* __restrict__ bmat,
    const float* __restrict__ I0, float* __restrict__ out)
{
  int64_t gid = (int64_t)blockIdx.x*256 + threadIdx.x;
  if (gid >= (int64_t)BATCH*TSTEPS*NN) return;
  int i = (int)(gid % NN);
  int64_t bt = gid / NN;
  const float4* xv = (const float4*)(x + bt*DDIM);
  const float4* bv = (const float4*)(bmat + (size_t)i*DDIM);
  float s = 0.f;
  #pragma unroll
  for (int q=0;q<DDIM/4;++q){
    float4 a = xv[q], w = bv[q];
    s = fmaf(a.x,w.x,s); s = fmaf(a.y,w.y,s);
    s = fmaf(a.z,w.z,s); s = fmaf(a.w,w.w,s);
  }
  out[gid] = DTC * (s + I0[i]);
}

// ---------- main simulator ----------
template<int CAP>
__device__ __forceinline__ void tbody(
    const uint32_t* __restrict__ ENTW, float* zs, float* pbuf,
    float* __restrict__ ob, int tid, int p, int r,
    uint32_t row, bool act, float c, float u,
    float al0,float al1,float al2,float al3,
    float g0,float g1,float g2,float g3)
{
  uint32_t ent[CAP];
  #pragma unroll
  for (int k=0;k<CAP;++k) ent[k] = ENTW[(size_t)k*STPB + tid];

  float s0=0.f,s1=0.f,s2=0.f,s3=0.f;
  for (int t=0; t<TSTEPS; ++t){
    if (act){
      float phi = 1.0f/(1.0f+__expf(-u));
      s0 = fmaf(al0, s0, g0*phi);
      s1 = fmaf(al1, s1, g1*phi);
      s2 = fmaf(al2, s2, g2*phi);
      s3 = fmaf(al3, s3, g3*phi);
      zs[row]      = s0+s1;
      zs[NN+row]   = s2+s3;
      zs[2*NN+row] = u;
    }
    __syncthreads();                         // z ready

    float stimv = 0.f;
    if (act) stimv = ob[(size_t)t*NN + row]; // precomputed DT*(stim+I0)

    float a[4] = {0.f,0.f,0.f,0.f};
    #pragma unroll
    for (int k=0;k<CAP;++k){
      uint32_t e  = ent[k];
      float val   = __uint_as_float(e & 0xFFFF0000u);
      float zv    = *(const float*)((const char*)zs + (e & 0xFFFFu));
      a[k&3] = fmaf(val, zv, a[k&3]);
    }
    float acc = (a[0]+a[1])+(a[2]+a[3]);
    if (p) pbuf[(p-1)*PTPB + r] = acc;
    __syncthreads();                         // partials ready

    if (act){
      float tot = acc + pbuf[r] + pbuf[PTPB + r];
      float un  = fmaf(c, u, tot + stimv);
      un = fminf(fmaxf(un, -UCLIP), UCLIP);
      u = un;
      ob[(size_t)t*NN + row] = u;
    }
  }
}

__global__ __launch_bounds__(STPB, 4) void sim_kernel(
    const float* __restrict__ u0, const uint8_t* __restrict__ ws,
    float* __restrict__ out)
{
  __shared__ float zs[3*NN + 36];   // [y_sv | y_dcv | u | zero pad x36]
  __shared__ float pbuf[2*PTPB];
  const uint32_t* ENTW = (const uint32_t*)(ws+ENT_OFF);
  const float*    CR   = (const float*)(ws+CR_OFF);
  const uint32_t* RR   = (const uint32_t*)(ws+RR_OFF);
  const float*    META = (const float*)(ws+META_OFF);

  int tid = threadIdx.x;
  int b   = blockIdx.x;
  int p   = tid / PTPB;
  int r   = tid - p*PTPB;
  int sw  = r >> 6;
  uint32_t row = RR[r];
  bool act = (p==0) && (row < NN);

  if (tid < 36) zs[3*NN + tid] = 0.f;   // pad-gather targets

  float al0=META[0], al1=META[1], al2=META[2], al3=META[3];
  float g0 =META[4], g1 =META[5], g2 =META[6], g3 =META[7];

  float c=0.f, u=0.f;
  if (act){ c = CR[r]; u = u0[(size_t)b*NN + row]; }
  float* ob = out + (size_t)b*TSTEPS*NN;

  switch (sw){
    case 0: tbody<CAP_0>(ENTW,zs,pbuf,ob,tid,p,r,row,act,c,u,al0,al1,al2,al3,g0,g1,g2,g3); break;
    case 1: tbody<CAP_1>(ENTW,zs,pbuf,ob,tid,p,r,row,act,c,u,al0,al1,al2,al3,g0,g1,g2,g3); break;
    case 2: tbody<CAP_2>(ENTW,zs,pbuf,ob,tid,p,r,row,act,c,u,al0,al1,al2,al3,g0,g1,g2,g3); break;
    case 3: tbody<CAP_3>(ENTW,zs,pbuf,ob,tid,p,r,row,act,c,u,al0,al1,al2,al3,g0,g1,g2,g3); break;
    default:tbody<CAP_4>(ENTW,zs,pbuf,ob,tid,p,r,row,act,c,u,al0,al1,al2,al3,g0,g1,g2,g3); break;
  }
}

extern "C" void kernel_launch(void* const* d_in, const int* in_sizes, int n_in,
                              void* d_out, int out_size, void* d_ws, size_t ws_size,
                              hipStream_t stream)
{
  const float* x      = (const float*)d_in[0];
  const float* u0v    = (const float*)d_in[1];
  const float* Te     = (const float*)d_in[2];
  const float* Tsv    = (const float*)d_in[3];
  const float* Tdcv   = (const float*)d_in[4];
  const float* Wsv    = (const float*)d_in[5];
  const float* Wdcv   = (const float*)d_in[6];
  const float* lamr   = (const float*)d_in[7];
  const float* Gr     = (const float*)d_in[8];
  const float* I0     = (const float*)d_in[9];
  const float* bmat   = (const float*)d_in[10];
  const float* asvr   = (const float*)d_in[11];
  const float* tausvr = (const float*)d_in[12];
  const float* adcvr  = (const float*)d_in[13];
  const float* taudcvr= (const float*)d_in[14];
  const int*   signt  = (const int*)d_in[15];
  uint8_t* ws = (uint8_t*)d_ws;

  hipLaunchKernelGGL(prepA_kernel, dim3(NN), dim3(64), 0, stream, Te, Tsv, Tdcv, ws);
  hipLaunchKernelGGL(prepB_kernel, dim3(1), dim3(PTPB), 0, stream,
      lamr, Gr, asvr, tausvr, adcvr, taudcvr, ws);
  hipLaunchKernelGGL(prepC_kernel, dim3(PTPB), dim3(64), 0, stream,
      Te, Tsv, Tdcv, Wsv, Wdcv, Gr, signt, ws);
  hipLaunchKernelGGL(stim_kernel,
      dim3((unsigned)(((int64_t)BATCH*TSTEPS*NN + 255)/256)), dim3(256), 0, stream,
      x, bmat, I0, (float*)d_out);
  hipLaunchKernelGGL(sim_kernel, dim3(BATCH), dim3(STPB), 0, stream,
      u0v, ws, (float*)d_out);
}

// Round 4
// 6794.241 us; speedup vs baseline: 1.0113x; 1.0113x over previous
//
#include <hip/hip_runtime.h>
#include <stdint.h>

// Stage2 neural-dynamics simulator, MI355X — round 4.
// 64 blocks (one per batch), 960 threads (3 parts x 320 rank slots, 15 waves).
// Entry slices live in VGPRs (compile-time caps per state-wave, fully unrolled
// gather loop) -> zero L2 traffic in the t-loop. Column-ordered entries
// (measured fewer LDS bank conflicts than bank-sorted+rotated, r2 vs r3).
// __launch_bounds__(960) ONLY: 15-wave block => compiler caps VGPR at 128
// (4 waves/SIMD), enough for ent[80]+working set without spill. r3's
// __launch_bounds__(960,4) forced VGPR=64 -> scratch spill -> 2x regression.
// Stim GEMM DT*(x@b^T + I0) precomputed into d_out.

#define NN      300
#define PTPB    320
#define STPB    960
#define TSTEPS  1000
#define DDIM    32
#define BATCH   64
#define DTC     0.01f
#define UCLIP   35.0f

#define CAP_0   80
#define CAP_1   72
#define CAP_2   68
#define CAP_3   64
#define CAP_4   60
__host__ __device__ __forceinline__ int capOf(int sw){
  return sw==0?CAP_0: sw==1?CAP_1: sw==2?CAP_2: sw==3?CAP_3: CAP_4;
}

// pad entry for rank rr: val=0 (top16), target zs[900+(rr&31)] (zeroed region)
#define PADOFF(rr) ((uint32_t)(3600 + (((rr)&31)<<2)))

// ws layout (bytes)
#define ENT_OFF   0
#define ENT_BYTES (CAP_0*STPB*4)           // 307200
#define CR_OFF    (ENT_OFF+ENT_BYTES)      // f32[320]  c = lam - DT*G*deg (rank order)
#define RR_OFF    (CR_OFF+PTPB*4)          // u32[320]  rank -> row
#define META_OFF  (RR_OFF+PTPB*4)          // f32[8]    alpha x4, gamma x4
#define LEN_OFF   (META_OFF+8*4)           // u32[320]  row nnz
#define DEG_OFF   (LEN_OFF+PTPB*4)         // f32[300]  gap degree
#define RANK_OFF  (DEG_OFF+NN*4)           // u32[300]  row -> rank

__device__ __forceinline__ float sigmoidf_(float x){ return 1.0f/(1.0f+__expf(-x)); }
__device__ __forceinline__ float softplusf_(float x){ return x>15.f ? x : log1pf(__expf(x)); }
__device__ __forceinline__ uint32_t bf16bits(float f){
  uint32_t v = __float_as_uint(f);
  return (v + 0x7FFFu + ((v>>16)&1u)) >> 16;   // RN-even
}

// ---------- prep A: per-row nnz + gap degree (grid 300 x 64) ----------
__global__ __launch_bounds__(64) void prepA_kernel(
    const float* __restrict__ Te, const float* __restrict__ Tsv,
    const float* __restrict__ Tdcv, uint8_t* __restrict__ ws)
{
  int i = blockIdx.x, lane = threadIdx.x;
  const float* te  = Te   + (size_t)i*NN;
  const float* tsv = Tsv  + (size_t)i*NN;
  const float* tdv = Tdcv + (size_t)i*NN;
  uint32_t cnt = 0; float deg = 0.f;
  for (int j=lane; j<NN; j+=64){
    float e = te[j];
    deg += e;
    cnt += (tsv[j]>0.f) + (tdv[j]>0.f) + (e>0.f);
  }
  for (int off=32; off; off>>=1){
    cnt += __shfl_down(cnt, off);
    deg += __shfl_down(deg, off);
  }
  if (lane==0){
    ((uint32_t*)(ws+LEN_OFF))[i] = cnt;
    ((float*)(ws+DEG_OFF))[i]    = deg;
  }
}

// ---------- prep B: ranking + scalars (1 block x 320) ----------
__global__ __launch_bounds__(PTPB) void prepB_kernel(
    const float* __restrict__ lamr, const float* __restrict__ Gr,
    const float* __restrict__ asvr, const float* __restrict__ tausvr,
    const float* __restrict__ adcvr, const float* __restrict__ taudcvr,
    uint8_t* __restrict__ ws)
{
  __shared__ uint32_t len_s[PTPB];
  __shared__ uint32_t rr_s[PTPB];
  int tid = threadIdx.x;
  uint32_t* LEN  = (uint32_t*)(ws+LEN_OFF);
  float*    DEG  = (float*)(ws+DEG_OFF);
  uint32_t* RANK = (uint32_t*)(ws+RANK_OFF);
  uint32_t* RR   = (uint32_t*)(ws+RR_OFF);
  float*    CR   = (float*)(ws+CR_OFF);
  float*    META = (float*)(ws+META_OFF);

  len_s[tid] = (tid<NN) ? LEN[tid] : 0u;
  rr_s[tid]  = 0xFFFFFFFFu;
  __syncthreads();
  uint32_t rank = 0;
  if (tid < NN){
    uint32_t li = len_s[tid];
    for (int j=0;j<NN;++j){
      uint32_t lj = len_s[j];
      rank += (lj>li || (lj==li && j<tid)) ? 1u:0u;
    }
    rr_s[rank] = (uint32_t)tid;
    RANK[tid]  = rank;
  }
  __syncthreads();
  RR[tid] = rr_s[tid];
  float G = 2.0f * sigmoidf_(Gr[0]);
  if (tid < NN){
    float lam = 0.9999f * sigmoidf_(lamr[tid]);
    CR[rank] = lam - DTC*G*DEG[tid];
  } else {
    CR[tid] = 0.f;
  }
  if (tid < 4){
    const float* ar = (tid<2)? asvr   : adcvr;
    const float* tr = (tid<2)? tausvr : taudcvr;
    int kk = tid & 1;
    float a   = 10.0f * sigmoidf_(ar[kk]);
    float tau = softplusf_(tr[kk]) + 1e-4f;
    float al  = __expf(-DTC/tau);
    META[tid]   = al;
    META[4+tid] = a*(1.0f-al);   // track s' = a*s
  }
}

// ---------- prep C: emit entries, column order, transposed layout (grid 320 x 64) ----------
// entry s of rank rr -> part s%3, slot s/3 -> ENT[slot*STPB + part*PTPB + rr]
__global__ __launch_bounds__(64) void prepC_kernel(
    const float* __restrict__ Te,  const float* __restrict__ Tsv,
    const float* __restrict__ Tdcv,const float* __restrict__ Wsv,
    const float* __restrict__ Wdcv,const float* __restrict__ Gr,
    const int*   __restrict__ signt, uint8_t* __restrict__ ws)
{
  int rr = blockIdx.x, lane = threadIdx.x;
  uint32_t* ENT = (uint32_t*)(ws+ENT_OFF);
  const uint32_t* RR = (const uint32_t*)(ws+RR_OFF);
  int sw  = rr >> 6;
  uint32_t cap3 = 3u*(uint32_t)capOf(sw);
  uint32_t row = RR[rr];

  if (row >= NN){                       // unowned rank slots: all pad
    for (uint32_t s=lane; s<cap3; s+=64)
      ENT[(size_t)(s/3u)*STPB + (s%3u)*PTPB + rr] = PADOFF(rr);
    return;
  }

  float G = 2.0f * sigmoidf_(Gr[0]);
  const float* te  = Te   + (size_t)row*NN;
  const float* tsv = Tsv  + (size_t)row*NN;
  const float* tdv = Tdcv + (size_t)row*NN;
  const float* wsv = Wsv  + (size_t)row*NN;
  const float* wdv = Wdcv + (size_t)row*NN;
  uint64_t lmask = ((uint64_t)1 << lane) - 1;
  uint32_t k = 0;
  for (int c0=0; c0<NN; c0+=64){       // SV segment
    int j = c0 + lane;
    bool on = (j<NN) && (tsv[j] > 0.f);
    uint64_t bal = __ballot(on);
    if (on){
      uint32_t s = k + (uint32_t)__popcll(bal & lmask);
      if (s < cap3){
        float sg = 2.0f*(float)signt[j] - 1.0f;
        float v  = DTC * sg * softplusf_(wsv[j]);
        ENT[(size_t)(s/3u)*STPB + (s%3u)*PTPB + rr] = (bf16bits(v)<<16) | (uint32_t)(j*4);
      }
    }
    k += (uint32_t)__popcll(bal);
  }
  for (int c0=0; c0<NN; c0+=64){       // DCV segment
    int j = c0 + lane;
    bool on = (j<NN) && (tdv[j] > 0.f);
    uint64_t bal = __ballot(on);
    if (on){
      uint32_t s = k + (uint32_t)__popcll(bal & lmask);
      if (s < cap3){
        float sg = 2.0f*(float)signt[j] - 1.0f;
        float v  = DTC * sg * softplusf_(wdv[j]);
        ENT[(size_t)(s/3u)*STPB + (s%3u)*PTPB + rr] = (bf16bits(v)<<16) | (uint32_t)((NN+j)*4);
      }
    }
    k += (uint32_t)__popcll(bal);
  }
  for (int c0=0; c0<NN; c0+=64){       // TE (gap) segment
    int j = c0 + lane;
    bool on = (j<NN) && (te[j] > 0.f);
    uint64_t bal = __ballot(on);
    if (on){
      uint32_t s = k + (uint32_t)__popcll(bal & lmask);
      if (s < cap3){
        float v = DTC * G * te[j];
        ENT[(size_t)(s/3u)*STPB + (s%3u)*PTPB + rr] = (bf16bits(v)<<16) | (uint32_t)((2*NN+j)*4);
      }
    }
    k += (uint32_t)__popcll(bal);
  }
  if (k > cap3) k = cap3;
  for (uint32_t s=k+lane; s<cap3; s+=64)  // pad the remaining (part,slot) pairs
    ENT[(size_t)(s/3u)*STPB + (s%3u)*PTPB + rr] = PADOFF(rr);
}

// ---------- stimulus: d_out[b,t,i] = DT * (dot(x[b,t,:], bmat[i,:]) + I0[i]) ----------
__global__ __launch_bounds__(256) void stim_kernel(
    const float* __restrict__ x, const float* __restrict__ bmat,
    const float* __restrict__ I0, float* __restrict__ out)
{
  int64_t gid = (int64_t)blockIdx.x*256 + threadIdx.x;
  if (gid >= (int64_t)BATCH*TSTEPS*NN) return;
  int i = (int)(gid % NN);
  int64_t bt = gid / NN;
  const float4* xv = (const float4*)(x + bt*DDIM);
  const float4* bv = (const float4*)(bmat + (size_t)i*DDIM);
  float s = 0.f;
  #pragma unroll
  for (int q=0;q<DDIM/4;++q){
    float4 a = xv[q], w = bv[q];
    s = fmaf(a.x,w.x,s); s = fmaf(a.y,w.y,s);
    s = fmaf(a.z,w.z,s); s = fmaf(a.w,w.w,s);
  }
  out[gid] = DTC * (s + I0[i]);
}

// ---------- main simulator ----------
template<int CAP>
__device__ __forceinline__ void tbody(
    const uint32_t* __restrict__ ENTW, float* zs, float* pbuf,
    float* __restrict__ ob, int tid, int p, int r,
    uint32_t row, bool act, float c, float u,
    float al0,float al1,float al2,float al3,
    float g0,float g1,float g2,float g3)
{
  uint32_t ent[CAP];
  #pragma unroll
  for (int k=0;k<CAP;++k) ent[k] = ENTW[(size_t)k*STPB + tid];

  float s0=0.f,s1=0.f,s2=0.f,s3=0.f;
  for (int t=0; t<TSTEPS; ++t){
    if (act){
      float phi = 1.0f/(1.0f+__expf(-u));
      s0 = fmaf(al0, s0, g0*phi);
      s1 = fmaf(al1, s1, g1*phi);
      s2 = fmaf(al2, s2, g2*phi);
      s3 = fmaf(al3, s3, g3*phi);
      zs[row]      = s0+s1;
      zs[NN+row]   = s2+s3;
      zs[2*NN+row] = u;
    }
    __syncthreads();                         // z ready

    float stimv = 0.f;
    if (act) stimv = ob[(size_t)t*NN + row]; // precomputed DT*(stim+I0)

    float a[4] = {0.f,0.f,0.f,0.f};
    #pragma unroll
    for (int k=0;k<CAP;++k){
      uint32_t e  = ent[k];
      float val   = __uint_as_float(e & 0xFFFF0000u);
      float zv    = *(const float*)((const char*)zs + (e & 0xFFFFu));
      a[k&3] = fmaf(val, zv, a[k&3]);
    }
    float acc = (a[0]+a[1])+(a[2]+a[3]);
    if (p) pbuf[(p-1)*PTPB + r] = acc;
    __syncthreads();                         // partials ready

    if (act){
      float tot = acc + pbuf[r] + pbuf[PTPB + r];
      float un  = fmaf(c, u, tot + stimv);
      un = fminf(fmaxf(un, -UCLIP), UCLIP);
      u = un;
      ob[(size_t)t*NN + row] = u;
    }
  }
}

__global__ __launch_bounds__(STPB) void sim_kernel(
    const float* __restrict__ u0, const uint8_t* __restrict__ ws,
    float* __restrict__ out)
{
  __shared__ float zs[3*NN + 36];   // [y_sv | y_dcv | u | zero pad x36]
  __shared__ float pbuf[2*PTPB];
  const uint32_t* ENTW = (const uint32_t*)(ws+ENT_OFF);
  const float*    CR   = (const float*)(ws+CR_OFF);
  const uint32_t* RR   = (const uint32_t*)(ws+RR_OFF);
  const float*    META = (const float*)(ws+META_OFF);

  int tid = threadIdx.x;
  int b   = blockIdx.x;
  int p   = tid / PTPB;
  int r   = tid - p*PTPB;
  int sw  = r >> 6;
  uint32_t row = RR[r];
  bool act = (p==0) && (row < NN);

  if (tid < 36) zs[3*NN + tid] = 0.f;   // pad-gather targets

  float al0=META[0], al1=META[1], al2=META[2], al3=META[3];
  float g0 =META[4], g1 =META[5], g2 =META[6], g3 =META[7];

  float c=0.f, u=0.f;
  if (act){ c = CR[r]; u = u0[(size_t)b*NN + row]; }
  float* ob = out + (size_t)b*TSTEPS*NN;

  switch (sw){
    case 0: tbody<CAP_0>(ENTW,zs,pbuf,ob,tid,p,r,row,act,c,u,al0,al1,al2,al3,g0,g1,g2,g3); break;
    case 1: tbody<CAP_1>(ENTW,zs,pbuf,ob,tid,p,r,row,act,c,u,al0,al1,al2,al3,g0,g1,g2,g3); break;
    case 2: tbody<CAP_2>(ENTW,zs,pbuf,ob,tid,p,r,row,act,c,u,al0,al1,al2,al3,g0,g1,g2,g3); break;
    case 3: tbody<CAP_3>(ENTW,zs,pbuf,ob,tid,p,r,row,act,c,u,al0,al1,al2,al3,g0,g1,g2,g3); break;
    default:tbody<CAP_4>(ENTW,zs,pbuf,ob,tid,p,r,row,act,c,u,al0,al1,al2,al3,g0,g1,g2,g3); break;
  }
}

extern "C" void kernel_launch(void* const* d_in, const int* in_sizes, int n_in,
                              void* d_out, int out_size, void* d_ws, size_t ws_size,
                              hipStream_t stream)
{
  const float* x      = (const float*)d_in[0];
  const float* u0v    = (const float*)d_in[1];
  const float* Te     = (const float*)d_in[2];
  const float* Tsv    = (const float*)d_in[3];
  const float* Tdcv   = (const float*)d_in[4];
  const float* Wsv    = (const float*)d_in[5];
  const float* Wdcv   = (const float*)d_in[6];
  const float* lamr   = (const float*)d_in[7];
  const float* Gr     = (const float*)d_in[8];
  const float* I0     = (const float*)d_in[9];
  const float* bmat   = (const float*)d_in[10];
  const float* asvr   = (const float*)d_in[11];
  const float* tausvr = (const float*)d_in[12];
  const float* adcvr  = (const float*)d_in[13];
  const float* taudcvr= (const float*)d_in[14];
  const int*   signt  = (const int*)d_in[15];
  uint8_t* ws = (uint8_t*)d_ws;

  hipLaunchKernelGGL(prepA_kernel, dim3(NN), dim3(64), 0, stream, Te, Tsv, Tdcv, ws);
  hipLaunchKernelGGL(prepB_kernel, dim3(1), dim3(PTPB), 0, stream,
      lamr, Gr, asvr, tausvr, adcvr, taudcvr, ws);
  hipLaunchKernelGGL(prepC_kernel, dim3(PTPB), dim3(64), 0, stream,
      Te, Tsv, Tdcv, Wsv, Wdcv, Gr, signt, ws);
  hipLaunchKernelGGL(stim_kernel,
      dim3((unsigned)(((int64_t)BATCH*TSTEPS*NN + 255)/256)), dim3(256), 0, stream,
      x, bmat, I0, (float*)d_out);
  hipLaunchKernelGGL(sim_kernel, dim3(BATCH), dim3(STPB), 0, stream,
      u0v, ws, (float*)d_out);
}